// Round 1
// baseline (456.709 us; speedup 1.0000x reference)
//
#include <hip/hip_runtime.h>
#include <hip/hip_bf16.h>
#include <math.h>

typedef __attribute__((ext_vector_type(8))) short bf16x8;
typedef __attribute__((ext_vector_type(4))) float f32x4;

__device__ __forceinline__ unsigned short f2b(float f) {
    union { float f; unsigned u; } a; a.f = f;
    unsigned r = a.u + 0x7FFFu + ((a.u >> 16) & 1u);
    return (unsigned short)(r >> 16);
}

// ---------------- cast x (fp32 -> bf16, same layout) ----------------
__global__ __launch_bounds__(256) void cast_x_kernel(const float* __restrict__ x,
                                                     unsigned short* __restrict__ xb, int n4) {
    int i = blockIdx.x * 256 + threadIdx.x;
    if (i >= n4) return;
    float4 v = ((const float4*)x)[i];
    ushort4 o;
    o.x = f2b(v.x); o.y = f2b(v.y); o.z = f2b(v.z); o.w = f2b(v.w);
    ((ushort4*)xb)[i] = o;
}

// ------------- transpose-cast: in [R][C] fp32 -> out [C][R] bf16 -------------
// block (32,8); grid (C/32, R/32, nmat)
__global__ __launch_bounds__(256) void transpose_cast_kernel(const float* __restrict__ in,
                                                             unsigned short* __restrict__ out,
                                                             int R, int C) {
    __shared__ float tile[32][33];
    size_t mo = (size_t)blockIdx.z * R * C;
    const float* src = in + mo;
    unsigned short* dst = out + mo;
    int c0 = blockIdx.x * 32, r0 = blockIdx.y * 32;
    int tx = threadIdx.x, ty = threadIdx.y;
#pragma unroll
    for (int i = 0; i < 32; i += 8)
        tile[ty + i][tx] = src[(size_t)(r0 + ty + i) * C + c0 + tx];
    __syncthreads();
#pragma unroll
    for (int i = 0; i < 32; i += 8)
        dst[(size_t)(c0 + ty + i) * R + r0 + tx] = f2b(tile[tx][ty + i]);
}

// ---------------- QKV GEMM ----------------
// A = xb [4096][2048] bf16, B^T = wt [48][128][2048] bf16 (mat*16+h blocks)
// out: q,k [B*H][T][Dh] bf16 ; v transposed: vt [B*H][Dh][T] bf16
constexpr int BKg = 64, LDKg = 72;

__global__ __launch_bounds__(256) void qkv_gemm_kernel(
    const unsigned short* __restrict__ xb,
    const unsigned short* __restrict__ wt,
    const float* __restrict__ bq, const float* __restrict__ bkb, const float* __restrict__ bvb,
    unsigned short* __restrict__ q, unsigned short* __restrict__ k, unsigned short* __restrict__ vt) {
    __shared__ unsigned short sA[128 * LDKg];
    __shared__ unsigned short sB[128 * LDKg];
    int cb = blockIdx.x;            // 0..47 : mat*16 + h
    int m0 = blockIdx.y * 128;      // row tile
    int tid = threadIdx.x;
    int lane = tid & 63, w = tid >> 6;
    int wm = w >> 1, wn = w & 1;
    int ln = lane & 15, quad = lane >> 4;
    int lr = tid >> 3;              // 0..31
    int lc = (tid & 7) * 8;         // 0..56

    f32x4 acc[4][4] = {};
    const unsigned short* aBase = xb + (size_t)m0 * 2048;
    const unsigned short* bBase = wt + (size_t)cb * 128 * 2048;

    for (int k0 = 0; k0 < 2048; k0 += BKg) {
#pragma unroll
        for (int p = 0; p < 4; ++p) {
            int row = lr + p * 32;
            *(bf16x8*)(sA + row * LDKg + lc) = *(const bf16x8*)(aBase + (size_t)row * 2048 + k0 + lc);
            *(bf16x8*)(sB + row * LDKg + lc) = *(const bf16x8*)(bBase + (size_t)row * 2048 + k0 + lc);
        }
        __syncthreads();
#pragma unroll
        for (int ks = 0; ks < 2; ++ks) {
            bf16x8 af[4], bfr[4];
#pragma unroll
            for (int i = 0; i < 4; ++i)
                af[i] = *(const bf16x8*)(sA + (wm * 64 + i * 16 + ln) * LDKg + ks * 32 + quad * 8);
#pragma unroll
            for (int i = 0; i < 4; ++i)
                bfr[i] = *(const bf16x8*)(sB + (wn * 64 + i * 16 + ln) * LDKg + ks * 32 + quad * 8);
#pragma unroll
            for (int i = 0; i < 4; ++i)
#pragma unroll
                for (int j = 0; j < 4; ++j)
                    acc[i][j] = __builtin_amdgcn_mfma_f32_16x16x32_bf16(af[i], bfr[j], acc[i][j], 0, 0, 0);
        }
        __syncthreads();
    }

    int mat = cb >> 4, h = cb & 15;
    const float* bias = (mat == 0) ? bq : (mat == 1) ? bkb : bvb;
    unsigned short* outqk = (mat == 0) ? q : k;
#pragma unroll
    for (int i = 0; i < 4; ++i) {
#pragma unroll
        for (int j = 0; j < 4; ++j) {
            int e = wn * 64 + j * 16 + ln;
            float bb = bias[h * 128 + e];
            if (mat < 2) {
#pragma unroll
                for (int r = 0; r < 4; ++r) {
                    int gr = m0 + wm * 64 + i * 16 + quad * 4 + r;
                    int b = gr >> 11, t = gr & 2047;
                    outqk[((size_t)(b * 16 + h) * 2048 + t) * 128 + e] = f2b(acc[i][j][r] + bb);
                }
            } else {
                int gr = m0 + wm * 64 + i * 16 + quad * 4;
                int b = gr >> 11, t = gr & 2047;
                ushort4 pk;
                pk.x = f2b(acc[i][j][0] + bb);
                pk.y = f2b(acc[i][j][1] + bb);
                pk.z = f2b(acc[i][j][2] + bb);
                pk.w = f2b(acc[i][j][3] + bb);
                *(ushort4*)(vt + ((size_t)(b * 16 + h) * 128 + e) * 2048 + t) = pk;
            }
        }
    }
}

// ---------------- Flash attention (causal) ----------------
// q,k: [32][2048][128] bf16 ; vt: [32][128][2048] bf16 ; o: [32][2048][128] bf16
__global__ __launch_bounds__(256) void attn_kernel(
    const unsigned short* __restrict__ qg,
    const unsigned short* __restrict__ kg,
    const unsigned short* __restrict__ vg,
    unsigned short* __restrict__ og) {
    constexpr int LDE = 136, LDV = 72, LDP = 72;
    __shared__ unsigned short sK[64 * LDE];
    __shared__ unsigned short sV[128 * LDV];
    __shared__ unsigned short sP[4 * 32 * LDP];

    int bh = blockIdx.x;                     // 0..31
    int t0 = (15 - (int)blockIdx.y) * 128;   // big tiles launched first
    int tid = threadIdx.x;
    int lane = tid & 63, w = tid >> 6;
    int ln = lane & 15, quad = lane >> 4;

    const unsigned short* qb = qg + (size_t)bh * 2048 * 128;
    const unsigned short* kb = kg + (size_t)bh * 2048 * 128;
    const unsigned short* vb = vg + (size_t)bh * 128 * 2048;

    bf16x8 qf[2][4];
#pragma unroll
    for (int i = 0; i < 2; ++i)
#pragma unroll
        for (int c = 0; c < 4; ++c)
            qf[i][c] = *(const bf16x8*)(qb + (size_t)(t0 + w * 32 + i * 16 + ln) * 128 + c * 32 + quad * 8);

    f32x4 oacc[2][8] = {};
    float mst[2][4], lst[2][4];
#pragma unroll
    for (int i = 0; i < 2; ++i)
#pragma unroll
        for (int r = 0; r < 4; ++r) { mst[i][r] = -INFINITY; lst[i][r] = 0.f; }

    int wtmax = t0 + w * 32 + 31;
    int nblk = (t0 + 128) / 64;
    const float scale = 0.08838834764831845f;

    for (int jb = 0; jb < nblk; ++jb) {
        int s0 = jb * 64;
        {   // stage K [64][128]
            int r_ = tid >> 4, c_ = (tid & 15) * 8;
#pragma unroll
            for (int p = 0; p < 4; ++p) {
                int row = r_ + p * 16;
                *(bf16x8*)(sK + row * LDE + c_) = *(const bf16x8*)(kb + (size_t)(s0 + row) * 128 + c_);
            }
            // stage V^T [128][64]
            int r2 = tid >> 3, c2 = (tid & 7) * 8;
#pragma unroll
            for (int p = 0; p < 4; ++p) {
                int row = r2 + p * 32;
                *(bf16x8*)(sV + row * LDV + c2) = *(const bf16x8*)(vb + (size_t)row * 2048 + s0 + c2);
            }
        }
        __syncthreads();
        if (s0 <= wtmax) {
            // S = Q K^T  (32 x 64 per wave)
            f32x4 sacc[2][4] = {};
#pragma unroll
            for (int c = 0; c < 4; ++c) {
                bf16x8 bfr[4];
#pragma unroll
                for (int j = 0; j < 4; ++j)
                    bfr[j] = *(const bf16x8*)(sK + (j * 16 + ln) * LDE + c * 32 + quad * 8);
#pragma unroll
                for (int i = 0; i < 2; ++i)
#pragma unroll
                    for (int j = 0; j < 4; ++j)
                        sacc[i][j] = __builtin_amdgcn_mfma_f32_16x16x32_bf16(qf[i][c], bfr[j], sacc[i][j], 0, 0, 0);
            }
            // online softmax per row
#pragma unroll
            for (int i = 0; i < 2; ++i) {
#pragma unroll
                for (int r = 0; r < 4; ++r) {
                    int t = t0 + w * 32 + i * 16 + quad * 4 + r;
                    float pv[4];
                    float rm = -INFINITY;
#pragma unroll
                    for (int j = 0; j < 4; ++j) {
                        int s = s0 + j * 16 + ln;
                        float vv = sacc[i][j][r] * scale;
                        if (s > t) vv = -INFINITY;
                        pv[j] = vv;
                        rm = fmaxf(rm, vv);
                    }
#pragma unroll
                    for (int m_ = 8; m_ >= 1; m_ >>= 1)
                        rm = fmaxf(rm, __shfl_xor(rm, m_, 64));
                    float mnew = fmaxf(mst[i][r], rm);
                    float alpha = __expf(mst[i][r] - mnew);
                    float rsum = 0.f;
#pragma unroll
                    for (int j = 0; j < 4; ++j) {
                        float p_ = __expf(pv[j] - mnew);
                        rsum += p_;
                        sP[(w * 32 + i * 16 + quad * 4 + r) * LDP + j * 16 + ln] = f2b(p_);
                    }
#pragma unroll
                    for (int m_ = 8; m_ >= 1; m_ >>= 1)
                        rsum += __shfl_xor(rsum, m_, 64);
                    lst[i][r] = lst[i][r] * alpha + rsum;
                    mst[i][r] = mnew;
#pragma unroll
                    for (int jj = 0; jj < 8; ++jj)
                        oacc[i][jj][r] *= alpha;
                }
            }
            // O += P V   (P: A-operand from LDS; V^T: B-operand)
#pragma unroll
            for (int c2_ = 0; c2_ < 2; ++c2_) {
                bf16x8 af[2], bfr[8];
#pragma unroll
                for (int i = 0; i < 2; ++i)
                    af[i] = *(const bf16x8*)(sP + (w * 32 + i * 16 + ln) * LDP + c2_ * 32 + quad * 8);
#pragma unroll
                for (int jj = 0; jj < 8; ++jj)
                    bfr[jj] = *(const bf16x8*)(sV + (jj * 16 + ln) * LDV + c2_ * 32 + quad * 8);
#pragma unroll
                for (int i = 0; i < 2; ++i)
#pragma unroll
                    for (int jj = 0; jj < 8; ++jj)
                        oacc[i][jj] = __builtin_amdgcn_mfma_f32_16x16x32_bf16(af[i], bfr[jj], oacc[i][jj], 0, 0, 0);
            }
        }
        __syncthreads();
    }

#pragma unroll
    for (int i = 0; i < 2; ++i) {
#pragma unroll
        for (int r = 0; r < 4; ++r) {
            int t = t0 + w * 32 + i * 16 + quad * 4 + r;
            float inv = 1.f / lst[i][r];
#pragma unroll
            for (int jj = 0; jj < 8; ++jj) {
                int e = jj * 16 + ln;
                og[((size_t)bh * 2048 + t) * 128 + e] = f2b(oacc[i][jj][r] * inv);
            }
        }
    }
}

// ---------------- Output projection GEMM ----------------
// A = o [32][2048][128] (b*16+h, t, e) ; B^T = wpt [2048][2048] ; out fp32 [4096][2048]
__global__ __launch_bounds__(256) void proj_gemm_kernel(
    const unsigned short* __restrict__ og,
    const unsigned short* __restrict__ wpt,
    const float* __restrict__ bp,
    float* __restrict__ out) {
    __shared__ unsigned short sA[128 * LDKg];
    __shared__ unsigned short sB[128 * LDKg];
    int cb = blockIdx.x;            // 0..15
    int m0 = blockIdx.y * 128;
    int b = m0 >> 11, t0_ = m0 & 2047;
    int tid = threadIdx.x;
    int lane = tid & 63, w = tid >> 6;
    int wm = w >> 1, wn = w & 1;
    int ln = lane & 15, quad = lane >> 4;
    int lr = tid >> 3, lc = (tid & 7) * 8;

    f32x4 acc[4][4] = {};
    const unsigned short* bBase = wpt + (size_t)cb * 128 * 2048;

    for (int k0 = 0; k0 < 2048; k0 += BKg) {
        int h = k0 >> 7, e0 = k0 & 127;
        const unsigned short* aBase = og + ((size_t)(b * 16 + h) * 2048 + t0_) * 128 + e0;
#pragma unroll
        for (int p = 0; p < 4; ++p) {
            int row = lr + p * 32;
            *(bf16x8*)(sA + row * LDKg + lc) = *(const bf16x8*)(aBase + (size_t)row * 128 + lc);
            *(bf16x8*)(sB + row * LDKg + lc) = *(const bf16x8*)(bBase + (size_t)row * 2048 + k0 + lc);
        }
        __syncthreads();
#pragma unroll
        for (int ks = 0; ks < 2; ++ks) {
            bf16x8 af[4], bfr[4];
#pragma unroll
            for (int i = 0; i < 4; ++i)
                af[i] = *(const bf16x8*)(sA + (wm * 64 + i * 16 + ln) * LDKg + ks * 32 + quad * 8);
#pragma unroll
            for (int i = 0; i < 4; ++i)
                bfr[i] = *(const bf16x8*)(sB + (wn * 64 + i * 16 + ln) * LDKg + ks * 32 + quad * 8);
#pragma unroll
            for (int i = 0; i < 4; ++i)
#pragma unroll
                for (int j = 0; j < 4; ++j)
                    acc[i][j] = __builtin_amdgcn_mfma_f32_16x16x32_bf16(af[i], bfr[j], acc[i][j], 0, 0, 0);
        }
        __syncthreads();
    }

#pragma unroll
    for (int i = 0; i < 4; ++i)
#pragma unroll
        for (int j = 0; j < 4; ++j) {
            int col = cb * 128 + wn * 64 + j * 16 + ln;
            float bias = bp[col];
#pragma unroll
            for (int r = 0; r < 4; ++r) {
                int row = m0 + wm * 64 + i * 16 + quad * 4 + r;
                out[(size_t)row * 2048 + col] = acc[i][j][r] + bias;
            }
        }
}

extern "C" void kernel_launch(void* const* d_in, const int* in_sizes, int n_in,
                              void* d_out, int out_size, void* d_ws, size_t ws_size,
                              hipStream_t stream) {
    const float* x  = (const float*)d_in[0];
    const float* Wq = (const float*)d_in[1];
    const float* bq = (const float*)d_in[2];
    const float* Wk = (const float*)d_in[3];
    const float* bk = (const float*)d_in[4];
    const float* Wv = (const float*)d_in[5];
    const float* bv = (const float*)d_in[6];
    const float* Wp = (const float*)d_in[7];
    const float* bp = (const float*)d_in[8];
    float* out = (float*)d_out;

    char* ws = (char*)d_ws;
    unsigned short* xb  = (unsigned short*)(ws);                 // 16 MB
    unsigned short* wt  = (unsigned short*)(ws + 16777216);      // 24 MB  [48][128][2048]
    unsigned short* wpt = (unsigned short*)(ws + 41943040);      // 8 MB   [2048][2048]
    unsigned short* q   = (unsigned short*)(ws + 50331648);      // 16 MB
    unsigned short* k   = (unsigned short*)(ws + 67108864);      // 16 MB
    unsigned short* vt  = (unsigned short*)(ws + 83886080);      // 16 MB
    unsigned short* o   = (unsigned short*)(ws + 100663296);     // 16 MB

    cast_x_kernel<<<8192, 256, 0, stream>>>(x, xb, 2097152);
    dim3 tb(32, 8);
    transpose_cast_kernel<<<dim3(4, 64, 16), tb, 0, stream>>>(Wq, wt, 2048, 128);
    transpose_cast_kernel<<<dim3(4, 64, 16), tb, 0, stream>>>(Wk, wt + 16 * 128 * 2048, 2048, 128);
    transpose_cast_kernel<<<dim3(4, 64, 16), tb, 0, stream>>>(Wv, wt + 32 * 128 * 2048, 2048, 128);
    transpose_cast_kernel<<<dim3(64, 64, 1), tb, 0, stream>>>(Wp, wpt, 2048, 2048);
    qkv_gemm_kernel<<<dim3(48, 32), 256, 0, stream>>>(xb, wt, bq, bk, bv, q, k, vt);
    attn_kernel<<<dim3(32, 16), 256, 0, stream>>>(q, k, vt, o);
    proj_gemm_kernel<<<dim3(16, 32), 256, 0, stream>>>(o, wpt, bp, out);
}